// Round 7
// baseline (120.329 us; speedup 1.0000x reference)
//
#include <hip/hip_runtime.h>

// Problem constants
#define HW 4096           // H*W
#define CHW 262144        // C*H*W
#define OUT_ELEMS 4194304 // B*C*H*W
#define FLT_BIG 3.4e38f

typedef __attribute__((ext_vector_type(8))) short  short8;   // MFMA A/B frag (4 VGPR)
typedef __attribute__((ext_vector_type(4))) float  floatx4;  // MFMA C/D frag
typedef __attribute__((ext_vector_type(4))) int    intx4;

// ws layout (NO zero-init needed anywhere -- every word read is either
// written first in-kernel or distinguishable-from-poison by magic value):
//   [0,8192)       ws_sse double[1024]   (per-block SSE, plain stores)
//   [8192,40960)   part u32[16][512]     (hist partials, agent atomic stores)
//   [40960,41024)  flags u32[16]         (magic completion flags)

__device__ __forceinline__ unsigned bf16_rne(float f) {
    unsigned u = __float_as_uint(f);
    return (u + 0x7FFFu + ((u >> 16) & 1u)) >> 16;  // RNE bf16 bits
}

__device__ __forceinline__ void split8(const float* f, intx4* hi, intx4* lo) {
    unsigned h[4], l[4];
#pragma unroll
    for (int j = 0; j < 4; ++j) {
        const unsigned h0 = bf16_rne(f[2 * j]);
        const unsigned h1 = bf16_rne(f[2 * j + 1]);
        const float hf0 = __uint_as_float(h0 << 16);
        const float hf1 = __uint_as_float(h1 << 16);
        const unsigned l0 = bf16_rne(f[2 * j] - hf0);
        const unsigned l1 = bf16_rne(f[2 * j + 1] - hf1);
        h[j] = h0 | (h1 << 16);
        l[j] = l0 | (l1 << 16);
    }
    *hi = intx4{(int)h[0], (int)h[1], (int)h[2], (int)h[3]};
    *lo = intx4{(int)l[0], (int)l[1], (int)l[2], (int)l[3]};
}

__device__ __forceinline__ void split4(float v0, float v1, float v2, float v3,
                                       int2* hi, int2* lo) {
    const unsigned h0 = bf16_rne(v0), h1 = bf16_rne(v1);
    const unsigned h2 = bf16_rne(v2), h3 = bf16_rne(v3);
    const unsigned l0 = bf16_rne(v0 - __uint_as_float(h0 << 16));
    const unsigned l1 = bf16_rne(v1 - __uint_as_float(h1 << 16));
    const unsigned l2 = bf16_rne(v2 - __uint_as_float(h2 << 16));
    const unsigned l3 = bf16_rne(v3 - __uint_as_float(h3 << 16));
    *hi = int2{(int)(h0 | (h1 << 16)), (int)(h2 | (h3 << 16))};
    *lo = int2{(int)(l0 | (l1 << 16)), (int)(l2 | (l3 << 16))};
}

// Main: R18 = R17 core with vq_prep DELETED. Each block stages RAW fp32 emb
// slices (coherent kernel input -- no cross-kernel pfrag coherence needed)
// and converts to split-bf16 fragment layout inline while writing LDS.
// enorm (-0.5||e||^2) computed in-block: per-thread 4-channel partial squares
// + 16-lane shfl_xor reduce, written to a double-buffered LDS array, consumed
// NEXT iteration (stays off the MFMA critical path, R13 rule). Redundant
// conversion (~1280 VALU/wave) < the ~4us dispatch-boundary it removes
// (R17 accounting: ~16us of gaps across 4 boundaries).
// Conversion mapping (verified against vq_prep's layout algebra):
//   thread t holds slice floats code=i*16+(t>>4), ch=4*(t&15)+k (coalesced
//   float4 loads); within-slice u16 idx = j*2048 + grp*512 + q*128 + n*8 + o
//   with grp=i, n=t>>4, jh=(t&15)>>3, q=((t&15)>>1)&3, o0=4*((t&15)&1);
//   lo plane at +8192 bytes. BLD reads byte = lane*16 + khalf*2048 + j*4096
//   + g*1024 (grp = khalf*2+g, lane = q*16+n) -- byte-exact match.
// Carried: swapped MFMA operands, 2-round butterfly, double-buffered cbuf,
// NO device atomics, 4 blocks/CU (LDS ~37.1 KB).
__global__ __launch_bounds__(256)
void vq_main(const float* __restrict__ x_in, const float* __restrict__ emb,
             float* __restrict__ out, float* __restrict__ idx_out,
             double* __restrict__ ws_sse) {
    __shared__ __align__(16) unsigned short cbuf[2][8192]; // 2 x 16 KB slices
    __shared__ __align__(16) float enorm_s[2][64];
    __shared__ float  b1s[2][64], b2s[2][64];
    __shared__ int    i1s[2][64], i2s[2][64];
    __shared__ int    c1i[64], c2i[64];
    __shared__ double parts[4][65];
    __shared__ double ls_red[4];

    const int t     = threadIdx.x;
    const int lane  = t & 63;
    const int wv    = t >> 6;           // 0..3
    const int col   = lane & 15;        // w-row within a 16-row M-tile
    const int quad  = lane >> 4;
    const int blk   = blockIdx.x;
    const int khalf = wv & 1;           // code-half of each 64-chunk
    const int mset  = wv >> 1;          // row-set: rows [mset*32, mset*32+32)
    const int ncol0 = khalf << 5;
    const int b = blk >> 6, h = blk & 63;
    const float* xb = x_in + (size_t)b * CHW + h * 64;

    // conversion-write byte offset within a slice (hi plane; lo = +8192)
    const int cvt_off = ((t & 15) >> 3) * 4096 + (((t & 15) >> 1) & 3) * 256
                      + (t >> 4) * 16 + ((t & 15) & 1) * 8;

    // ---- issue slice-0 staging loads FIRST (latency hides under split8) ----
    float4 s0[4];
#pragma unroll
    for (int i = 0; i < 4; ++i)
        s0[i] = *(const float4*)(emb + (i << 10) + (t << 2));

    // ---- X-frags: TWO 16-row M-tiles, direct from BCHW global (coalesced),
    // split-bf16, register-resident. Used as the MFMA *B* operand. ----
    short8 Xh[2][2], Xl[2][2];          // [tile][c-half]
#pragma unroll
    for (int T = 0; T < 2; ++T) {
        const int row = (mset << 5) + (T << 4) + col;
#pragma unroll
        for (int u = 0; u < 2; ++u) {
            float f[8];
#pragma unroll
            for (int j = 0; j < 8; ++j) {
                const int c = (u << 5) + (quad << 3) + j;
                f[j] = xb[(size_t)c * HW + row];
            }
            intx4 hi, lo;
            split8(f, &hi, &lo);
            Xh[T][u] = __builtin_bit_cast(short8, hi);
            Xl[T][u] = __builtin_bit_cast(short8, lo);
        }
    }

    // ---- convert + store slice 0 (cbuf[0] + enorm_s[0]) ----
    {
        char* cbn = (char*)&cbuf[0][0];
        float ss[4];
#pragma unroll
        for (int i = 0; i < 4; ++i) {
            const float4 v = s0[i];
            int2 hi, lo;
            split4(v.x, v.y, v.z, v.w, &hi, &lo);
            *(int2*)(cbn + cvt_off + (i << 10))        = hi;
            *(int2*)(cbn + cvt_off + (i << 10) + 8192) = lo;
            ss[i] = fmaf(v.x, v.x, fmaf(v.y, v.y, fmaf(v.z, v.z, v.w * v.w)));
        }
#pragma unroll
        for (int off = 1; off <= 8; off <<= 1) {
#pragma unroll
            for (int i = 0; i < 4; ++i) ss[i] += __shfl_xor(ss[i], off, 64);
        }
        if ((lane & 15) == 0) {
#pragma unroll
            for (int i = 0; i < 4; ++i)
                enorm_s[0][(i << 4) + (t >> 4)] = -0.5f * ss[i];
        }
    }
    __syncthreads();

    // Per-tile, two top-2 tracks (a0/a1) for ILP; merged before butterfly.
    float B1a[2], B2a[2], B1b[2], B2b[2];
    int   I1a[2], I2a[2], I1b[2], I2b[2];
#pragma unroll
    for (int T = 0; T < 2; ++T) {
        B1a[T] = -FLT_BIG; B2a[T] = -FLT_BIG; B1b[T] = -FLT_BIG; B2b[T] = -FLT_BIG;
        I1a[T] = 0x3FFFFFFF; I2a[T] = 0x3FFFFFFF; I1b[T] = 0x3FFFFFFF; I2b[T] = 0x3FFFFFFF;
    }

    const int lbo = (khalf << 11) + (lane << 4);   // within-slice lane base

#pragma unroll 2
    for (int nc = 0; nc < 8; ++nc) {
        const int cur = nc & 1;
        // early-issue next slice's raw loads (converted after compute)
        float4 st[4];
        if (nc < 7) {
#pragma unroll
            for (int i = 0; i < 4; ++i)
                st[i] = *(const float4*)(emb + ((nc + 1) << 12) + (i << 10) + (t << 2));
        }
        const int K0 = nc << 6;
        // -0.5*||e||^2 for this lane's 8 codes (from LDS, produced last iter)
        const floatx4 e0v = *(const floatx4*)&enorm_s[cur][ncol0 + (quad << 2)];
        const floatx4 e1v = *(const floatx4*)&enorm_s[cur][ncol0 + (quad << 2) + 16];
        floatx4 a0[2] = {{0.f,0.f,0.f,0.f},{0.f,0.f,0.f,0.f}};
        floatx4 a1[2] = {{0.f,0.f,0.f,0.f},{0.f,0.f,0.f,0.f}};
        const char* base = (const char*)&cbuf[cur][0] + lbo;
#define BLD(j, g) (*(const short8*)(base + ((j) << 12) + ((g) << 10)))
        {   // j=0: eh c[0,32) x {xh,xl}, both tiles
            const short8 e0 = BLD(0, 0), e1 = BLD(0, 1);
#pragma unroll
            for (int T = 0; T < 2; ++T) {
                a0[T] = __builtin_amdgcn_mfma_f32_16x16x32_bf16(e0, Xh[T][0], a0[T], 0, 0, 0);
                a1[T] = __builtin_amdgcn_mfma_f32_16x16x32_bf16(e1, Xh[T][0], a1[T], 0, 0, 0);
                a0[T] = __builtin_amdgcn_mfma_f32_16x16x32_bf16(e0, Xl[T][0], a0[T], 0, 0, 0);
                a1[T] = __builtin_amdgcn_mfma_f32_16x16x32_bf16(e1, Xl[T][0], a1[T], 0, 0, 0);
            }
        }
        {   // j=1: eh c[32,64) x {xh,xl}, both tiles
            const short8 e0 = BLD(1, 0), e1 = BLD(1, 1);
#pragma unroll
            for (int T = 0; T < 2; ++T) {
                a0[T] = __builtin_amdgcn_mfma_f32_16x16x32_bf16(e0, Xh[T][1], a0[T], 0, 0, 0);
                a1[T] = __builtin_amdgcn_mfma_f32_16x16x32_bf16(e1, Xh[T][1], a1[T], 0, 0, 0);
                a0[T] = __builtin_amdgcn_mfma_f32_16x16x32_bf16(e0, Xl[T][1], a0[T], 0, 0, 0);
                a1[T] = __builtin_amdgcn_mfma_f32_16x16x32_bf16(e1, Xl[T][1], a1[T], 0, 0, 0);
            }
        }
        {   // j=2: el c[0,32) x xh, both tiles
            const short8 e0 = BLD(2, 0), e1 = BLD(2, 1);
#pragma unroll
            for (int T = 0; T < 2; ++T) {
                a0[T] = __builtin_amdgcn_mfma_f32_16x16x32_bf16(e0, Xh[T][0], a0[T], 0, 0, 0);
                a1[T] = __builtin_amdgcn_mfma_f32_16x16x32_bf16(e1, Xh[T][0], a1[T], 0, 0, 0);
            }
        }
        {   // j=3: el c[32,64) x xh, both tiles
            const short8 e0 = BLD(3, 0), e1 = BLD(3, 1);
#pragma unroll
            for (int T = 0; T < 2; ++T) {
                a0[T] = __builtin_amdgcn_mfma_f32_16x16x32_bf16(e0, Xh[T][1], a0[T], 0, 0, 0);
                a1[T] = __builtin_amdgcn_mfma_f32_16x16x32_bf16(e1, Xh[T][1], a1[T], 0, 0, 0);
            }
        }
#undef BLD

        const int cb = K0 + ncol0 + (quad << 2);
#pragma unroll
        for (int T = 0; T < 2; ++T) {
#pragma unroll
            for (int reg = 0; reg < 4; ++reg) {
                const float da = a0[T][reg] + e0v[reg];   // = dot - ||e||^2/2 = -d/2
                if (da > B1a[T])      { B2a[T] = B1a[T]; I2a[T] = I1a[T]; B1a[T] = da; I1a[T] = cb + reg; }
                else if (da > B2a[T]) { B2a[T] = da; I2a[T] = cb + reg; }
                const float db = a1[T][reg] + e1v[reg];
                if (db > B1b[T])      { B2b[T] = B1b[T]; I2b[T] = I1b[T]; B1b[T] = db; I1b[T] = cb + 16 + reg; }
                else if (db > B2b[T]) { B2b[T] = db; I2b[T] = cb + 16 + reg; }
            }
        }

        // convert + write next slice into the other buffer; barrier covers
        // both the ds_writes (producers) and this iteration's reads.
        if (nc < 7) {
            char* cbn = (char*)&cbuf[cur ^ 1][0];
            float ss[4];
#pragma unroll
            for (int i = 0; i < 4; ++i) {
                const float4 v = st[i];
                int2 hi, lo;
                split4(v.x, v.y, v.z, v.w, &hi, &lo);
                *(int2*)(cbn + cvt_off + (i << 10))        = hi;
                *(int2*)(cbn + cvt_off + (i << 10) + 8192) = lo;
                ss[i] = fmaf(v.x, v.x, fmaf(v.y, v.y, fmaf(v.z, v.z, v.w * v.w)));
            }
#pragma unroll
            for (int off = 1; off <= 8; off <<= 1) {
#pragma unroll
                for (int i = 0; i < 4; ++i) ss[i] += __shfl_xor(ss[i], off, 64);
            }
            if ((lane & 15) == 0) {
#pragma unroll
                for (int i = 0; i < 4; ++i)
                    enorm_s[cur ^ 1][(i << 4) + (t >> 4)] = -0.5f * ss[i];
            }
        }
        __syncthreads();
    }

    // ---- per tile: merge tracks, then cross-lane top-2 butterfly over
    // QUADS only (off 16,32); disjoint code sets, explicit index tie-break ----
#pragma unroll
    for (int T = 0; T < 2; ++T) {
        float B1, B2; int I1, I2;
        if (B1b[T] > B1a[T] || (B1b[T] == B1a[T] && I1b[T] < I1a[T])) {
            B1 = B1b[T]; I1 = I1b[T];
            if (B1a[T] > B2b[T] || (B1a[T] == B2b[T] && I1a[T] < I2b[T])) { B2 = B1a[T]; I2 = I1a[T]; }
            else                                                          { B2 = B2b[T]; I2 = I2b[T]; }
        } else {
            B1 = B1a[T]; I1 = I1a[T];
            if (B1b[T] > B2a[T] || (B1b[T] == B2a[T] && I1b[T] < I2a[T])) { B2 = B1b[T]; I2 = I1b[T]; }
            else                                                          { B2 = B2a[T]; I2 = I2a[T]; }
        }
#pragma unroll
        for (int off = 16; off <= 32; off <<= 1) {
            const float ob1 = __shfl_xor(B1, off, 64);
            const int   oi1 = __shfl_xor(I1, off, 64);
            const float ob2 = __shfl_xor(B2, off, 64);
            const int   oi2 = __shfl_xor(I2, off, 64);
            if (ob1 > B1 || (ob1 == B1 && oi1 < I1)) {
                float nb2; int ni2;
                if (B1 > ob2 || (B1 == ob2 && I1 < oi2)) { nb2 = B1; ni2 = I1; }
                else                                     { nb2 = ob2; ni2 = oi2; }
                B1 = ob1; I1 = oi1; B2 = nb2; I2 = ni2;
            } else if (ob1 > B2 || (ob1 == B2 && oi1 < I2)) {
                B2 = ob1; I2 = oi1;
            }
        }
        if (lane < 16) {
            const int row = (mset << 5) + (T << 4) + lane;
            b1s[khalf][row] = B1; b2s[khalf][row] = B2;
            i1s[khalf][row] = I1; i2s[khalf][row] = I2;
        }
    }
    __syncthreads();

    // ---- merge halves -> approx top-2 candidates per row (max-flipped) ----
    if (t < 64) {
        const int r = t;
        float b1 = b1s[0][r], b2 = b2s[0][r];
        int   i1 = i1s[0][r], i2 = i2s[0][r];
        const float c1 = b1s[1][r]; const int j1 = i1s[1][r];
        const float c2 = b2s[1][r]; const int j2 = i2s[1][r];
        if (c1 > b1 || (c1 == b1 && j1 < i1))      { b2 = b1; i2 = i1; b1 = c1; i1 = j1; }
        else if (c1 > b2 || (c1 == b2 && j1 < i2)) { b2 = c1; i2 = j1; }
        if (c2 > b2 || (c2 == b2 && j2 < i2))      { b2 = c2; i2 = j2; }
        c1i[r] = i1; c2i[r] = i2;
    }
    __syncthreads();

    // ---- unconditional 4-way-parallel exact fp64 verify of both candidates:
    // thread group k = t>>6 -> candidate (k&1), c-half (k>>1), 32 c each ----
    const int r = t & 63;
    const int k = t >> 6;
    {
        const int ch = k >> 1;
        const int code = (k & 1) ? c2i[r] : c1i[r];
        const float* ep = emb + ((size_t)code << 6) + (ch << 5);
        const float* xq = xb + r;   // lanes r consecutive -> coalesced
        double d0 = 0.0, d1 = 0.0;
#pragma unroll
        for (int cc = 0; cc < 32; cc += 2) {
            const int c = (ch << 5) + cc;
            const double f0 = (double)xq[(size_t)c * HW]       - (double)ep[cc];
            const double f1 = (double)xq[(size_t)(c + 1) * HW] - (double)ep[cc + 1];
            d0 = fma(f0, f0, d0);
            d1 = fma(f1, f1, d1);
        }
        parts[k][r] = d0 + d1;
    }
    __syncthreads();

    // ---- finalize (all threads, redundant per row: LDS broadcast reads) ----
    int win;
    {
        const double d1 = parts[0][r] + parts[2][r];
        const double d2 = parts[1][r] + parts[3][r];
        win = c1i[r];
        const int i2 = c2i[r];
        if (d2 < d1 || (d2 == d1 && i2 < win)) win = i2; // lowest-index tie-break
        if (t < 64) idx_out[(blk << 6) + r] = (float)win;
    }

    // ---- epilogue: quantized out (coalesced along w) + per-block SSE ----
    {
        const int c0 = k << 4;           // 16 channels per thread-group
        const float* xp = xb + r;
        float*       op = out + (size_t)b * CHW + h * 64 + r;
        const float* eq = emb + ((size_t)win << 6);
        float sse_local = 0.f;
#pragma unroll
        for (int cc = 0; cc < 16; ++cc) {
            const int c = c0 + cc;
            const float qc = eq[c];
            const float dx = qc - xp[(size_t)c * HW];
            sse_local = fmaf(dx, dx, sse_local);
            op[(size_t)c * HW] = qc;
        }
#pragma unroll
        for (int off = 32; off > 0; off >>= 1)
            sse_local += __shfl_down(sse_local, off, 64);
        if (lane == 0) ls_red[wv] = (double)sse_local;
        __syncthreads();
        if (t == 0)
            ws_sse[blk] = (ls_red[0] + ls_red[1]) + (ls_red[2] + ls_red[3]);  // plain store
    }
}

// hist2: 16 blocks x 256 threads. LDS histogram of 4096 indices each,
// partials published via agent-scope atomic stores (write-through, no fence,
// no zero-init), then a MAGIC completion flag per block. Each block reads all
// 16 flags after publishing; whoever sees all 16 (the last publisher always
// does) computes the three scalars -- idempotent, race-free, needs no done
// counter and no pre-zeroed state (the harness's per-iteration workspace
// fill re-poisons flags; poison can't match 16 distinct magic values).
__global__ void vq_hist2(const float* __restrict__ idx_out,
                         const double* __restrict__ ws_sse,
                         const float* __restrict__ weight,
                         unsigned* __restrict__ part,
                         unsigned* __restrict__ flags,
                         float* __restrict__ scal) {
    __shared__ unsigned hs[512];
    __shared__ double redt[4], reds[4];
    __shared__ int    redi[4], lastf;
    const int t = threadIdx.x;
    const int blk = blockIdx.x;
    const int lane = t & 63, wv = t >> 6;
    hs[t] = 0u; hs[t + 256] = 0u;
    __syncthreads();
    const float4* ip = (const float4*)(idx_out + (blk << 12));
#pragma unroll
    for (int i = 0; i < 4; ++i) {
        const float4 v = ip[(i << 8) + t];    // coalesced
        atomicAdd(&hs[(int)v.x], 1u);         // LDS atomics
        atomicAdd(&hs[(int)v.y], 1u);
        atomicAdd(&hs[(int)v.z], 1u);
        atomicAdd(&hs[(int)v.w], 1u);
    }
    __syncthreads();
    __hip_atomic_store(&part[(blk << 9) + t],       hs[t],
                       __ATOMIC_RELAXED, __HIP_MEMORY_SCOPE_AGENT);
    __hip_atomic_store(&part[(blk << 9) + t + 256], hs[t + 256],
                       __ATOMIC_RELAXED, __HIP_MEMORY_SCOPE_AGENT);
    __syncthreads();   // each thread's stores drained (vmcnt0) before barrier
    if (t == 0) {
        __hip_atomic_store(&flags[blk], 0x51C0FFEEu ^ (unsigned)blk,
                           __ATOMIC_RELAXED, __HIP_MEMORY_SCOPE_AGENT);
        asm volatile("s_waitcnt vmcnt(0)" ::: "memory");
        int all = 1;
#pragma unroll
        for (int p = 0; p < 16; ++p)
            all &= (__hip_atomic_load(&flags[p], __ATOMIC_RELAXED,
                                      __HIP_MEMORY_SCOPE_AGENT)
                    == (0x51C0FFEEu ^ (unsigned)p)) ? 1 : 0;
        lastf = all;
    }
    __syncthreads();
    if (lastf) {
        double term = 0.0, ssep = 0.0; int act = 0;
#pragma unroll
        for (int j = 0; j < 2; ++j) {
            const int kk = t + (j << 8);
            unsigned cnt = 0;
#pragma unroll
            for (int p = 0; p < 16; ++p)
                cnt += __hip_atomic_load(&part[(p << 9) + kk], __ATOMIC_RELAXED,
                                         __HIP_MEMORY_SCOPE_AGENT);
            const double pr = (double)cnt * (1.0 / 65536.0);
            term += pr * log(pr + 1e-10);
            act  += (weight[kk] >= 0.01f) ? 1 : 0;
        }
#pragma unroll
        for (int j = 0; j < 4; ++j) ssep += ws_sse[t + (j << 8)];   // coalesced
#pragma unroll
        for (int off = 32; off > 0; off >>= 1) {
            term += __shfl_down(term, off, 64);
            ssep += __shfl_down(ssep, off, 64);
            act  += __shfl_down(act,  off, 64);
        }
        if (lane == 0) { redt[wv] = term; reds[wv] = ssep; redi[wv] = act; }
        __syncthreads();
        if (t == 0) {
            const double s  = (redt[0] + redt[1]) + (redt[2] + redt[3]);
            const double ss = (reds[0] + reds[1]) + (reds[2] + reds[3]);
            const int    a  = redi[0] + redi[1] + redi[2] + redi[3];
            scal[0] = (float)(ss * (1.0 / 4194304.0));  // commitment_loss
            scal[1] = (float)exp(-s);                   // perplexity
            scal[2] = (float)a;                         // active_codes
        }
    }
}

extern "C" void kernel_launch(void* const* d_in, const int* in_sizes, int n_in,
                              void* d_out, int out_size, void* d_ws, size_t ws_size,
                              hipStream_t stream) {
    const float* x      = (const float*)d_in[0];  // [16,64,64,64] fp32
    const float* emb    = (const float*)d_in[1];  // [512,64] fp32
    const float* weight = (const float*)d_in[2];  // [512] fp32

    float* out = (float*)d_out;
    double*   ws_sse = (double*)d_ws;
    unsigned* part   = (unsigned*)((char*)d_ws + 8192);
    unsigned* flags  = (unsigned*)((char*)d_ws + 40960);

    float* scal    = out + OUT_ELEMS;      // commitment, perplexity, active
    float* idx_out = out + OUT_ELEMS + 3;  // indices as float [65536]

    vq_main<<<1024, 256, 0, stream>>>(x, emb, out, idx_out, ws_sse);
    vq_hist2<<<16, 256, 0, stream>>>(idx_out, ws_sse, weight, part, flags, scal);
}

// Round 8
// 101.592 us; speedup vs baseline: 1.1844x; 1.1844x over previous
//
#include <hip/hip_runtime.h>

// Problem constants
#define HW 4096           // H*W
#define CHW 262144        // C*H*W
#define OUT_ELEMS 4194304 // B*C*H*W
#define FLT_BIG 3.4e38f

typedef __attribute__((ext_vector_type(8))) short  short8;   // MFMA A/B frag (4 VGPR)
typedef __attribute__((ext_vector_type(4))) float  floatx4;  // MFMA C/D frag
typedef __attribute__((ext_vector_type(4))) int    intx4;

// ws layout:
//   [0,2048)        enorm f32[512]   -- holds -0.5*||e||^2 (prescaled)
//   [4096,135168)   planes_frag u16 (128 KB, fragment-major split-bf16 codebook)
//   [135168,143360) ws_sse double[1024]  (per-block SSE, plain stores)
//   [143360,145408) hist u32[512]    (device-atomic accumulated histogram)
//   [145408,145412) done u32         (hist2 block completion counter)
// hist/done zeroed by vq_prep block 0 each launch (graph-replay safe).

__device__ __forceinline__ unsigned bf16_rne(float f) {
    unsigned u = __float_as_uint(f);
    return (u + 0x7FFFu + ((u >> 16) & 1u)) >> 16;  // RNE bf16 bits
}

__device__ __forceinline__ void split8(const float* f, intx4* hi, intx4* lo) {
    unsigned h[4], l[4];
#pragma unroll
    for (int j = 0; j < 4; ++j) {
        const unsigned h0 = bf16_rne(f[2 * j]);
        const unsigned h1 = bf16_rne(f[2 * j + 1]);
        const float hf0 = __uint_as_float(h0 << 16);
        const float hf1 = __uint_as_float(h1 << 16);
        const unsigned l0 = bf16_rne(f[2 * j] - hf0);
        const unsigned l1 = bf16_rne(f[2 * j + 1] - hf1);
        h[j] = h0 | (h1 << 16);
        l[j] = l0 | (l1 << 16);
    }
    *hi = intx4{(int)h[0], (int)h[1], (int)h[2], (int)h[3]};
    *lo = intx4{(int)l[0], (int)l[1], (int)l[2], (int)l[3]};
}

// prep: 128 blocks x 256 threads; 4 codes/block (1 wave per code), single
// iteration. enorm stored PRESCALED as -0.5*||e||^2. Block 0 also zeroes
// hist/done for the fused hist2 tail.
// R18 post-mortem: inline conversion in vq_main cost +16.5us (7.3M LDS bank
// conflicts on the scattered cvt ds_writes + redundant split/shfl VALU in all
// 1024 blocks) vs ~5.5us saved from the removed boundary. prep stays.
__global__ void vq_prep(const float* __restrict__ emb,
                        unsigned short* __restrict__ pfrag,
                        float* __restrict__ enorm,
                        unsigned* __restrict__ hist,
                        unsigned* __restrict__ done) {
    const int t = threadIdx.x;
    const int lane = t & 63;
    if (blockIdx.x == 0) {
        hist[t] = 0u; hist[t + 256] = 0u;
        if (t == 0) *done = 0u;
    }
    const int code = (blockIdx.x << 2) + (t >> 6);
    const int c = lane;
    const float v = emb[(code << 6) + c];            // 256B coalesced per wave
    const unsigned hb = bf16_rne(v);
    const float hf    = __uint_as_float(hb << 16);
    const unsigned lb = bf16_rne(v - hf);
    const int nc = code >> 6, grp = (code & 63) >> 4, n = code & 15;
    const int q = (c & 31) >> 3, o = c & 7;
    const int jh = c >> 5;        // eh element e=c
    const int jl = 2 + (c >> 5);  // el element e=64+c
    pfrag[((((size_t)(nc*4 + jh)*4 + grp)*4 + q)*16 + n)*8 + o] = (unsigned short)hb;
    pfrag[((((size_t)(nc*4 + jl)*4 + grp)*4 + q)*16 + n)*8 + o] = (unsigned short)lb;
    float s = v * v;
#pragma unroll
    for (int off = 32; off > 0; off >>= 1) s += __shfl_xor(s, off, 64);
    if (lane == 0) enorm[code] = -0.5f * s;
}

// Main: R19 = R17 core (1024 blocks x 256 thr, 2 tiles/wave, LDS-staged
// codebook) with the tail de-duplicated: the exact fp64 verify ALREADY
// computes the winner's squared distance, so ws_sse is reduced directly from
// parts[] (fp64, one wave, 6 shfl) and the epilogue shrinks to pure
// emb[win] -> out stores. Deleted: 16 strided x re-loads + 16 fmaf + fp32
// shfl reduce + ls_red + one __syncthreads per block. Slightly MORE accurate
// (fp64 SSE accumulation).
// Carried: swapped MFMA operands (codes=A, x=B), enorm off the MFMA critical
// path, 2-round butterfly, double-buffered conflict-free staging copy,
// NO device atomics in this kernel.
__global__ __launch_bounds__(256)
void vq_main(const float* __restrict__ x_in, const float* __restrict__ emb,
             const unsigned short* __restrict__ pfrag,
             const float* __restrict__ enorm,
             float* __restrict__ out, float* __restrict__ idx_out,
             double* __restrict__ ws_sse) {
    __shared__ __align__(16) unsigned short cbuf[2][8192];   // 2 x 16 KB slices
    __shared__ float  b1s[2][64], b2s[2][64];
    __shared__ int    i1s[2][64], i2s[2][64];
    __shared__ int    c1i[64], c2i[64];
    __shared__ double parts[4][65];

    const int t     = threadIdx.x;
    const int lane  = t & 63;
    const int wv    = t >> 6;           // 0..3
    const int col   = lane & 15;        // w-row within a 16-row M-tile
    const int quad  = lane >> 4;
    const int blk   = blockIdx.x;
    const int khalf = wv & 1;           // code-half of each 64-chunk
    const int mset  = wv >> 1;          // row-set: rows [mset*32, mset*32+32)
    const int ncol0 = khalf << 5;
    const int b = blk >> 6, h = blk & 63;
    const float* xb = x_in + (size_t)b * CHW + h * 64;

    // ---- issue slice-0 staging loads FIRST (latency hides under split8) ----
    intx4 s0[4];
#pragma unroll
    for (int i = 0; i < 4; ++i)
        s0[i] = *(const intx4*)((const char*)pfrag + (i << 12) + (t << 4));

    // ---- X-frags: TWO 16-row M-tiles, direct from BCHW global (coalesced),
    // split-bf16, register-resident. Used as the MFMA *B* operand. ----
    short8 Xh[2][2], Xl[2][2];          // [tile][c-half]
#pragma unroll
    for (int T = 0; T < 2; ++T) {
        const int row = (mset << 5) + (T << 4) + col;
#pragma unroll
        for (int u = 0; u < 2; ++u) {
            float f[8];
#pragma unroll
            for (int j = 0; j < 8; ++j) {
                const int c = (u << 5) + (quad << 3) + j;
                f[j] = xb[(size_t)c * HW + row];
            }
            intx4 hi, lo;
            split8(f, &hi, &lo);
            Xh[T][u] = __builtin_bit_cast(short8, hi);
            Xl[T][u] = __builtin_bit_cast(short8, lo);
        }
    }

    // ---- write slice 0 into LDS buffer 0 (linear t<<4: conflict-free) ----
#pragma unroll
    for (int i = 0; i < 4; ++i)
        *(intx4*)((char*)&cbuf[0][0] + (i << 12) + (t << 4)) = s0[i];
    __syncthreads();

    // Per-tile, two top-2 tracks (a0/a1) for ILP; merged before butterfly.
    float B1a[2], B2a[2], B1b[2], B2b[2];
    int   I1a[2], I2a[2], I1b[2], I2b[2];
#pragma unroll
    for (int T = 0; T < 2; ++T) {
        B1a[T] = -FLT_BIG; B2a[T] = -FLT_BIG; B1b[T] = -FLT_BIG; B2b[T] = -FLT_BIG;
        I1a[T] = 0x3FFFFFFF; I2a[T] = 0x3FFFFFFF; I1b[T] = 0x3FFFFFFF; I2b[T] = 0x3FFFFFFF;
    }

    const float* enp = enorm + ncol0 + (quad << 2);
    const int lbo = (khalf << 11) + (lane << 4);   // within-slice lane base

#pragma unroll 2
    for (int nc = 0; nc < 8; ++nc) {
        const int cur = nc & 1;
        // early-issue next slice's global loads (consumed after compute)
        intx4 st[4];
        if (nc < 7) {
#pragma unroll
            for (int i = 0; i < 4; ++i)
                st[i] = *(const intx4*)((const char*)pfrag +
                          ((size_t)(nc + 1) << 14) + (i << 12) + (t << 4));
        }
        const int K0 = nc << 6;
        // -0.5*||e||^2 for this lane's 8 codes; shared by BOTH tiles.
        const floatx4 e0v = *(const floatx4*)(enp + K0);
        const floatx4 e1v = *(const floatx4*)(enp + K0 + 16);
        floatx4 a0[2] = {{0.f,0.f,0.f,0.f},{0.f,0.f,0.f,0.f}};
        floatx4 a1[2] = {{0.f,0.f,0.f,0.f},{0.f,0.f,0.f,0.f}};
        const char* base = (const char*)&cbuf[cur][0] + lbo;
#define BLD(j, g) (*(const short8*)(base + ((j) << 12) + ((g) << 10)))
        {   // j=0: eh c[0,32) x {xh,xl}, both tiles
            const short8 e0 = BLD(0, 0), e1 = BLD(0, 1);
#pragma unroll
            for (int T = 0; T < 2; ++T) {
                a0[T] = __builtin_amdgcn_mfma_f32_16x16x32_bf16(e0, Xh[T][0], a0[T], 0, 0, 0);
                a1[T] = __builtin_amdgcn_mfma_f32_16x16x32_bf16(e1, Xh[T][0], a1[T], 0, 0, 0);
                a0[T] = __builtin_amdgcn_mfma_f32_16x16x32_bf16(e0, Xl[T][0], a0[T], 0, 0, 0);
                a1[T] = __builtin_amdgcn_mfma_f32_16x16x32_bf16(e1, Xl[T][0], a1[T], 0, 0, 0);
            }
        }
        {   // j=1: eh c[32,64) x {xh,xl}, both tiles
            const short8 e0 = BLD(1, 0), e1 = BLD(1, 1);
#pragma unroll
            for (int T = 0; T < 2; ++T) {
                a0[T] = __builtin_amdgcn_mfma_f32_16x16x32_bf16(e0, Xh[T][1], a0[T], 0, 0, 0);
                a1[T] = __builtin_amdgcn_mfma_f32_16x16x32_bf16(e1, Xh[T][1], a1[T], 0, 0, 0);
                a0[T] = __builtin_amdgcn_mfma_f32_16x16x32_bf16(e0, Xl[T][1], a0[T], 0, 0, 0);
                a1[T] = __builtin_amdgcn_mfma_f32_16x16x32_bf16(e1, Xl[T][1], a1[T], 0, 0, 0);
            }
        }
        {   // j=2: el c[0,32) x xh, both tiles
            const short8 e0 = BLD(2, 0), e1 = BLD(2, 1);
#pragma unroll
            for (int T = 0; T < 2; ++T) {
                a0[T] = __builtin_amdgcn_mfma_f32_16x16x32_bf16(e0, Xh[T][0], a0[T], 0, 0, 0);
                a1[T] = __builtin_amdgcn_mfma_f32_16x16x32_bf16(e1, Xh[T][0], a1[T], 0, 0, 0);
            }
        }
        {   // j=3: el c[32,64) x xh, both tiles
            const short8 e0 = BLD(3, 0), e1 = BLD(3, 1);
#pragma unroll
            for (int T = 0; T < 2; ++T) {
                a0[T] = __builtin_amdgcn_mfma_f32_16x16x32_bf16(e0, Xh[T][1], a0[T], 0, 0, 0);
                a1[T] = __builtin_amdgcn_mfma_f32_16x16x32_bf16(e1, Xh[T][1], a1[T], 0, 0, 0);
            }
        }
#undef BLD

        const int cb = K0 + ncol0 + (quad << 2);
#pragma unroll
        for (int T = 0; T < 2; ++T) {
#pragma unroll
            for (int reg = 0; reg < 4; ++reg) {
                const float da = a0[T][reg] + e0v[reg];   // = dot - ||e||^2/2 = -d/2
                if (da > B1a[T])      { B2a[T] = B1a[T]; I2a[T] = I1a[T]; B1a[T] = da; I1a[T] = cb + reg; }
                else if (da > B2a[T]) { B2a[T] = da; I2a[T] = cb + reg; }
                const float db = a1[T][reg] + e1v[reg];
                if (db > B1b[T])      { B2b[T] = B1b[T]; I2b[T] = I1b[T]; B1b[T] = db; I1b[T] = cb + 16 + reg; }
                else if (db > B2b[T]) { B2b[T] = db; I2b[T] = cb + 16 + reg; }
            }
        }

        // write next slice into the other buffer; barrier covers both the
        // ds_writes (producers) and this iteration's ds_reads (consumers).
        if (nc < 7) {
#pragma unroll
            for (int i = 0; i < 4; ++i)
                *(intx4*)((char*)&cbuf[cur ^ 1][0] + (i << 12) + (t << 4)) = st[i];
        }
        __syncthreads();
    }

    // ---- per tile: merge tracks, then cross-lane top-2 butterfly over
    // QUADS only (off 16,32); disjoint code sets, explicit index tie-break ----
#pragma unroll
    for (int T = 0; T < 2; ++T) {
        float B1, B2; int I1, I2;
        if (B1b[T] > B1a[T] || (B1b[T] == B1a[T] && I1b[T] < I1a[T])) {
            B1 = B1b[T]; I1 = I1b[T];
            if (B1a[T] > B2b[T] || (B1a[T] == B2b[T] && I1a[T] < I2b[T])) { B2 = B1a[T]; I2 = I1a[T]; }
            else                                                          { B2 = B2b[T]; I2 = I2b[T]; }
        } else {
            B1 = B1a[T]; I1 = I1a[T];
            if (B1b[T] > B2a[T] || (B1b[T] == B2a[T] && I1b[T] < I2a[T])) { B2 = B1b[T]; I2 = I1b[T]; }
            else                                                          { B2 = B2a[T]; I2 = I2a[T]; }
        }
#pragma unroll
        for (int off = 16; off <= 32; off <<= 1) {
            const float ob1 = __shfl_xor(B1, off, 64);
            const int   oi1 = __shfl_xor(I1, off, 64);
            const float ob2 = __shfl_xor(B2, off, 64);
            const int   oi2 = __shfl_xor(I2, off, 64);
            if (ob1 > B1 || (ob1 == B1 && oi1 < I1)) {
                float nb2; int ni2;
                if (B1 > ob2 || (B1 == ob2 && I1 < oi2)) { nb2 = B1; ni2 = I1; }
                else                                     { nb2 = ob2; ni2 = oi2; }
                B1 = ob1; I1 = oi1; B2 = nb2; I2 = ni2;
            } else if (ob1 > B2 || (ob1 == B2 && oi1 < I2)) {
                B2 = ob1; I2 = oi1;
            }
        }
        if (lane < 16) {
            const int row = (mset << 5) + (T << 4) + lane;
            b1s[khalf][row] = B1; b2s[khalf][row] = B2;
            i1s[khalf][row] = I1; i2s[khalf][row] = I2;
        }
    }
    __syncthreads();

    // ---- merge halves -> approx top-2 candidates per row (max-flipped) ----
    if (t < 64) {
        const int r = t;
        float b1 = b1s[0][r], b2 = b2s[0][r];
        int   i1 = i1s[0][r], i2 = i2s[0][r];
        const float c1 = b1s[1][r]; const int j1 = i1s[1][r];
        const float c2 = b2s[1][r]; const int j2 = i2s[1][r];
        if (c1 > b1 || (c1 == b1 && j1 < i1))      { b2 = b1; i2 = i1; b1 = c1; i1 = j1; }
        else if (c1 > b2 || (c1 == b2 && j1 < i2)) { b2 = c1; i2 = j1; }
        if (c2 > b2 || (c2 == b2 && j2 < i2))      { b2 = c2; i2 = j2; }
        c1i[r] = i1; c2i[r] = i2;
    }
    __syncthreads();

    // ---- unconditional 4-way-parallel exact fp64 verify of both candidates:
    // thread group k = t>>6 -> candidate (k&1), c-half (k>>1), 32 c each ----
    const int r = t & 63;
    const int k = t >> 6;
    {
        const int ch = k >> 1;
        const int code = (k & 1) ? c2i[r] : c1i[r];
        const float* ep = emb + ((size_t)code << 6) + (ch << 5);
        const float* xq = xb + r;   // lanes r consecutive -> coalesced
        double d0 = 0.0, d1 = 0.0;
#pragma unroll
        for (int cc = 0; cc < 32; cc += 2) {
            const int c = (ch << 5) + cc;
            const double f0 = (double)xq[(size_t)c * HW]       - (double)ep[cc];
            const double f1 = (double)xq[(size_t)(c + 1) * HW] - (double)ep[cc + 1];
            d0 = fma(f0, f0, d0);
            d1 = fma(f1, f1, d1);
        }
        parts[k][r] = d0 + d1;
    }
    __syncthreads();

    // ---- finalize: winner + EXACT fp64 SSE straight from parts[] (R19: the
    // verify already computed the winner's distance -- no x re-read) ----
    int win; double dwin;
    {
        const double d1 = parts[0][r] + parts[2][r];
        const double d2 = parts[1][r] + parts[3][r];
        win = c1i[r]; dwin = d1;
        const int i2 = c2i[r];
        if (d2 < d1 || (d2 == d1 && i2 < win)) { win = i2; dwin = d2; } // lowest-index tie-break
    }
    if (t < 64) {
        idx_out[(blk << 6) + r] = (float)win;
        double s = dwin;
#pragma unroll
        for (int off = 32; off > 0; off >>= 1) s += __shfl_down(s, off, 64);
        if (t == 0) ws_sse[blk] = s;    // plain store
    }

    // ---- epilogue: quantized out only (no SSE, no x reads) ----
    {
        const int c0 = k << 4;           // 16 channels per thread-group
        float*       op = out + (size_t)b * CHW + h * 64 + r;
        const float* eq = emb + ((size_t)win << 6) + c0;
#pragma unroll
        for (int cc = 0; cc < 16; ++cc)
            op[(size_t)(c0 + cc) * HW] = eq[cc];
    }
}

// hist2: 16 blocks x 256 threads. LDS histogram of 4096 indices each, pushed
// into a global hist via device atomicAdd (8K adds total), then a done-counter
// last block computes all three scalars. Fence-free R13 pattern (R17-proven).
__global__ void vq_hist2(const float* __restrict__ idx_out,
                         const double* __restrict__ ws_sse,
                         const float* __restrict__ weight,
                         unsigned* __restrict__ hist,
                         unsigned* __restrict__ done,
                         float* __restrict__ scal) {
    __shared__ unsigned hs[512];
    __shared__ double redt[4], reds[4];
    __shared__ int    redi[4], lastf;
    const int t = threadIdx.x;
    const int lane = t & 63, wv = t >> 6;
    hs[t] = 0u; hs[t + 256] = 0u;
    __syncthreads();
    const float4* ip = (const float4*)(idx_out + (blockIdx.x << 12));
#pragma unroll
    for (int i = 0; i < 4; ++i) {
        const float4 v = ip[(i << 8) + t];    // coalesced
        atomicAdd(&hs[(int)v.x], 1u);         // LDS atomics
        atomicAdd(&hs[(int)v.y], 1u);
        atomicAdd(&hs[(int)v.z], 1u);
        atomicAdd(&hs[(int)v.w], 1u);
    }
    __syncthreads();
    if (hs[t])       atomicAdd(&hist[t],       hs[t]);
    if (hs[t + 256]) atomicAdd(&hist[t + 256], hs[t + 256]);
    __syncthreads();   // drains every thread's global atomics (vmcnt 0)

    if (t == 0) {
        lastf = (__hip_atomic_fetch_add(done, 1u, __ATOMIC_RELAXED,
                                        __HIP_MEMORY_SCOPE_AGENT) == 15u) ? 1 : 0;
    }
    __syncthreads();
    if (lastf) {
        double term = 0.0, ssep = 0.0; int act = 0;
#pragma unroll
        for (int j = 0; j < 2; ++j) {
            const int kk = t + (j << 8);
            const unsigned cnt =
                __hip_atomic_load(&hist[kk], __ATOMIC_RELAXED, __HIP_MEMORY_SCOPE_AGENT);
            const double pr = (double)cnt * (1.0 / 65536.0);
            term += pr * log(pr + 1e-10);
            act  += (weight[kk] >= 0.01f) ? 1 : 0;
        }
#pragma unroll
        for (int j = 0; j < 4; ++j) ssep += ws_sse[t + (j << 8)];   // coalesced
#pragma unroll
        for (int off = 32; off > 0; off >>= 1) {
            term += __shfl_down(term, off, 64);
            ssep += __shfl_down(ssep, off, 64);
            act  += __shfl_down(act,  off, 64);
        }
        if (lane == 0) { redt[wv] = term; reds[wv] = ssep; redi[wv] = act; }
        __syncthreads();
        if (t == 0) {
            const double s  = (redt[0] + redt[1]) + (redt[2] + redt[3]);
            const double ss = (reds[0] + reds[1]) + (reds[2] + reds[3]);
            const int    a  = redi[0] + redi[1] + redi[2] + redi[3];
            scal[0] = (float)(ss * (1.0 / 4194304.0));  // commitment_loss
            scal[1] = (float)exp(-s);                   // perplexity
            scal[2] = (float)a;                         // active_codes
        }
    }
}

extern "C" void kernel_launch(void* const* d_in, const int* in_sizes, int n_in,
                              void* d_out, int out_size, void* d_ws, size_t ws_size,
                              hipStream_t stream) {
    const float* x      = (const float*)d_in[0];  // [16,64,64,64] fp32
    const float* emb    = (const float*)d_in[1];  // [512,64] fp32
    const float* weight = (const float*)d_in[2];  // [512] fp32

    float* out = (float*)d_out;
    float*          enorm  = (float*)d_ws;
    unsigned short* pfrag  = (unsigned short*)((char*)d_ws + 4096);
    double*         ws_sse = (double*)((char*)d_ws + 135168);
    unsigned*       hist   = (unsigned*)((char*)d_ws + 143360);
    unsigned*       done   = (unsigned*)((char*)d_ws + 145408);

    float* scal    = out + OUT_ELEMS;      // commitment, perplexity, active
    float* idx_out = out + OUT_ELEMS + 3;  // indices as float [65536]

    vq_prep<<<128, 256, 0, stream>>>(emb, pfrag, enorm, hist, done);
    vq_main<<<1024, 256, 0, stream>>>(x, emb, pfrag, enorm, out, idx_out, ws_sse);
    vq_hist2<<<16, 256, 0, stream>>>(idx_out, ws_sse, weight, hist, done, scal);
}

// Round 10
// 100.006 us; speedup vs baseline: 1.2032x; 1.0159x over previous
//
#include <hip/hip_runtime.h>

// Problem constants
#define HW 4096           // H*W
#define CHW 262144        // C*H*W
#define OUT_ELEMS 4194304 // B*C*H*W

typedef __attribute__((ext_vector_type(8))) short  short8;   // MFMA A/B frag (4 VGPR)
typedef __attribute__((ext_vector_type(4))) float  floatx4;  // MFMA C/D frag
typedef __attribute__((ext_vector_type(4))) int    intx4;

// ws layout:
//   [0,2048)        enorm f32[512]   -- holds -0.5*||e||^2 (prescaled)
//   [4096,135168)   planes_frag u16 (128 KB, fragment-major split-bf16 codebook)
//   [135168,143360) ws_sse double[1024]  (per-block SSE, plain stores)
//   [143360,145408) hist u32[512]    (device-atomic accumulated histogram)
//   [145408,145412) done u32         (hist2 block completion counter)
// hist/done zeroed by vq_prep block 0 each launch (graph-replay safe).

__device__ __forceinline__ unsigned bf16_rne(float f) {
    unsigned u = __float_as_uint(f);
    return (u + 0x7FFFu + ((u >> 16) & 1u)) >> 16;  // RNE bf16 bits
}

__device__ __forceinline__ void split8(const float* f, intx4* hi, intx4* lo) {
    unsigned h[4], l[4];
#pragma unroll
    for (int j = 0; j < 4; ++j) {
        const unsigned h0 = bf16_rne(f[2 * j]);
        const unsigned h1 = bf16_rne(f[2 * j + 1]);
        const float hf0 = __uint_as_float(h0 << 16);
        const float hf1 = __uint_as_float(h1 << 16);
        const unsigned l0 = bf16_rne(f[2 * j] - hf0);
        const unsigned l1 = bf16_rne(f[2 * j + 1] - hf1);
        h[j] = h0 | (h1 << 16);
        l[j] = l0 | (l1 << 16);
    }
    *hi = intx4{(int)h[0], (int)h[1], (int)h[2], (int)h[3]};
    *lo = intx4{(int)l[0], (int)l[1], (int)l[2], (int)l[3]};
}

// prep: 128 blocks x 256 threads; 4 codes/block (1 wave per code), single
// iteration. enorm stored PRESCALED as -0.5*||e||^2. Block 0 also zeroes
// hist/done for the fused hist2 tail.
__global__ void vq_prep(const float* __restrict__ emb,
                        unsigned short* __restrict__ pfrag,
                        float* __restrict__ enorm,
                        unsigned* __restrict__ hist,
                        unsigned* __restrict__ done) {
    const int t = threadIdx.x;
    const int lane = t & 63;
    if (blockIdx.x == 0) {
        hist[t] = 0u; hist[t + 256] = 0u;
        if (t == 0) *done = 0u;
    }
    const int code = (blockIdx.x << 2) + (t >> 6);
    const int c = lane;
    const float v = emb[(code << 6) + c];            // 256B coalesced per wave
    const unsigned hb = bf16_rne(v);
    const float hf    = __uint_as_float(hb << 16);
    const unsigned lb = bf16_rne(v - hf);
    const int nc = code >> 6, grp = (code & 63) >> 4, n = code & 15;
    const int q = (c & 31) >> 3, o = c & 7;
    const int jh = c >> 5;        // eh element e=c
    const int jl = 2 + (c >> 5);  // el element e=64+c
    pfrag[((((size_t)(nc*4 + jh)*4 + grp)*4 + q)*16 + n)*8 + o] = (unsigned short)hb;
    pfrag[((((size_t)(nc*4 + jl)*4 + grp)*4 + q)*16 + n)*8 + o] = (unsigned short)lb;
    float s = v * v;
#pragma unroll
    for (int off = 32; off > 0; off >>= 1) s += __shfl_xor(s, off, 64);
    if (lane == 0) enorm[code] = -0.5f * s;
}

// Main: R21 = R19 + HYBRID packed-key selection.
// R20 post-mortem: 9-bit mantissa theft perturbed scores by up to 511 ULP
// (3.9e-3 at |score|~64) -- 8x the intrinsic split-bf16 error (~5e-4) -- and
// knocked the true winner out of the approx top-2 for >=1 of 65536 rows.
// Fix: steal only 5 bits in the HOT insert loop (local ordinal nc*4+reg,
// an inline constant per unrolled iteration): perturbation 31 ULP = 2.4e-4,
// BELOW the intrinsic error the top-2 + exact-fp64-verify scheme has absorbed
// across 9 passing rounds. The COLD merges (track/butterfly/halves, ~10 ops
// each) unpack to (masked score, exact global code) and use R19's proven
// float+index compare chains -- no further masking, no added perturbation,
// explicit lowest-code tie-break at every stage. fp64 verify unchanged.
//   key = (score_bits & ~31) | ord;  scores <= 0 so smaller uint = better.
//   insert: t=max(p,K1); K1=min(p,K1); K2=min(t,K2)   (4 VALU vs ~8)
//   unpack: code = (ord>>2)*64 + ncol0 + quad*4 + (ord&3)  [+16 for track b]
// Carried from R17/R19: 1024 blocks x 256 thr, 2 tiles/wave, LDS-staged
// double-buffered codebook (conflict-free linear copy), enorm off the MFMA
// critical path, ws_sse from parts[] (no x re-read), NO device atomics.
__global__ __launch_bounds__(256)
void vq_main(const float* __restrict__ x_in, const float* __restrict__ emb,
             const unsigned short* __restrict__ pfrag,
             const float* __restrict__ enorm,
             float* __restrict__ out, float* __restrict__ idx_out,
             double* __restrict__ ws_sse) {
    __shared__ __align__(16) unsigned short cbuf[2][8192];   // 2 x 16 KB slices
    __shared__ float  b1s[2][64], b2s[2][64];
    __shared__ int    i1s[2][64], i2s[2][64];
    __shared__ int    c1i[64], c2i[64];
    __shared__ double parts[4][65];

    const int t     = threadIdx.x;
    const int lane  = t & 63;
    const int wv    = t >> 6;           // 0..3
    const int col   = lane & 15;        // w-row within a 16-row M-tile
    const int quad  = lane >> 4;
    const int blk   = blockIdx.x;
    const int khalf = wv & 1;           // code-half of each 64-chunk
    const int mset  = wv >> 1;          // row-set: rows [mset*32, mset*32+32)
    const int ncol0 = khalf << 5;
    const int b = blk >> 6, h = blk & 63;
    const float* xb = x_in + (size_t)b * CHW + h * 64;

    // ---- issue slice-0 staging loads FIRST (latency hides under split8) ----
    intx4 s0[4];
#pragma unroll
    for (int i = 0; i < 4; ++i)
        s0[i] = *(const intx4*)((const char*)pfrag + (i << 12) + (t << 4));

    // ---- X-frags: TWO 16-row M-tiles, direct from BCHW global (coalesced),
    // split-bf16, register-resident. Used as the MFMA *B* operand. ----
    short8 Xh[2][2], Xl[2][2];          // [tile][c-half]
#pragma unroll
    for (int T = 0; T < 2; ++T) {
        const int row = (mset << 5) + (T << 4) + col;
#pragma unroll
        for (int u = 0; u < 2; ++u) {
            float f[8];
#pragma unroll
            for (int j = 0; j < 8; ++j) {
                const int c = (u << 5) + (quad << 3) + j;
                f[j] = xb[(size_t)c * HW + row];
            }
            intx4 hi, lo;
            split8(f, &hi, &lo);
            Xh[T][u] = __builtin_bit_cast(short8, hi);
            Xl[T][u] = __builtin_bit_cast(short8, lo);
        }
    }

    // ---- write slice 0 into LDS buffer 0 (linear t<<4: conflict-free) ----
#pragma unroll
    for (int i = 0; i < 4; ++i)
        *(intx4*)((char*)&cbuf[0][0] + (i << 12) + (t << 4)) = s0[i];
    __syncthreads();

    // Packed-key top-2 state (5-bit local ordinal): per tile, two tracks.
    unsigned K1a[2], K2a[2], K1b[2], K2b[2];
#pragma unroll
    for (int T = 0; T < 2; ++T) {
        K1a[T] = 0xFFFFFFFFu; K2a[T] = 0xFFFFFFFFu;
        K1b[T] = 0xFFFFFFFFu; K2b[T] = 0xFFFFFFFFu;
    }

    const float* enp = enorm + ncol0 + (quad << 2);
    const int lbo = (khalf << 11) + (lane << 4);   // within-slice lane base

#pragma unroll 2
    for (int nc = 0; nc < 8; ++nc) {
        const int cur = nc & 1;
        // early-issue next slice's global loads (consumed after compute)
        intx4 st[4];
        if (nc < 7) {
#pragma unroll
            for (int i = 0; i < 4; ++i)
                st[i] = *(const intx4*)((const char*)pfrag +
                          ((size_t)(nc + 1) << 14) + (i << 12) + (t << 4));
        }
        const int K0 = nc << 6;
        // -0.5*||e||^2 for this lane's 8 codes; shared by BOTH tiles.
        const floatx4 e0v = *(const floatx4*)(enp + K0);
        const floatx4 e1v = *(const floatx4*)(enp + K0 + 16);
        floatx4 a0[2] = {{0.f,0.f,0.f,0.f},{0.f,0.f,0.f,0.f}};
        floatx4 a1[2] = {{0.f,0.f,0.f,0.f},{0.f,0.f,0.f,0.f}};
        const char* base = (const char*)&cbuf[cur][0] + lbo;
#define BLD(j, g) (*(const short8*)(base + ((j) << 12) + ((g) << 10)))
        {   // j=0: eh c[0,32) x {xh,xl}, both tiles
            const short8 e0 = BLD(0, 0), e1 = BLD(0, 1);
#pragma unroll
            for (int T = 0; T < 2; ++T) {
                a0[T] = __builtin_amdgcn_mfma_f32_16x16x32_bf16(e0, Xh[T][0], a0[T], 0, 0, 0);
                a1[T] = __builtin_amdgcn_mfma_f32_16x16x32_bf16(e1, Xh[T][0], a1[T], 0, 0, 0);
                a0[T] = __builtin_amdgcn_mfma_f32_16x16x32_bf16(e0, Xl[T][0], a0[T], 0, 0, 0);
                a1[T] = __builtin_amdgcn_mfma_f32_16x16x32_bf16(e1, Xl[T][0], a1[T], 0, 0, 0);
            }
        }
        {   // j=1: eh c[32,64) x {xh,xl}, both tiles
            const short8 e0 = BLD(1, 0), e1 = BLD(1, 1);
#pragma unroll
            for (int T = 0; T < 2; ++T) {
                a0[T] = __builtin_amdgcn_mfma_f32_16x16x32_bf16(e0, Xh[T][1], a0[T], 0, 0, 0);
                a1[T] = __builtin_amdgcn_mfma_f32_16x16x32_bf16(e1, Xh[T][1], a1[T], 0, 0, 0);
                a0[T] = __builtin_amdgcn_mfma_f32_16x16x32_bf16(e0, Xl[T][1], a0[T], 0, 0, 0);
                a1[T] = __builtin_amdgcn_mfma_f32_16x16x32_bf16(e1, Xl[T][1], a1[T], 0, 0, 0);
            }
        }
        {   // j=2: el c[0,32) x xh, both tiles
            const short8 e0 = BLD(2, 0), e1 = BLD(2, 1);
#pragma unroll
            for (int T = 0; T < 2; ++T) {
                a0[T] = __builtin_amdgcn_mfma_f32_16x16x32_bf16(e0, Xh[T][0], a0[T], 0, 0, 0);
                a1[T] = __builtin_amdgcn_mfma_f32_16x16x32_bf16(e1, Xh[T][0], a1[T], 0, 0, 0);
            }
        }
        {   // j=3: el c[32,64) x xh, both tiles
            const short8 e0 = BLD(3, 0), e1 = BLD(3, 1);
#pragma unroll
            for (int T = 0; T < 2; ++T) {
                a0[T] = __builtin_amdgcn_mfma_f32_16x16x32_bf16(e0, Xh[T][1], a0[T], 0, 0, 0);
                a1[T] = __builtin_amdgcn_mfma_f32_16x16x32_bf16(e1, Xh[T][1], a1[T], 0, 0, 0);
            }
        }
#undef BLD

        // write next slice into the other buffer BEFORE selection (selection
        // depends on MFMA results; the ds_writes don't).
        if (nc < 7) {
#pragma unroll
            for (int i = 0; i < 4; ++i)
                *(intx4*)((char*)&cbuf[cur ^ 1][0] + (i << 12) + (t << 4)) = st[i];
        }

#pragma unroll
        for (int T = 0; T < 2; ++T) {
#pragma unroll
            for (int reg = 0; reg < 4; ++reg) {
                const unsigned ord = (unsigned)((nc << 2) + reg);  // inline const
                const float da = a0[T][reg] + e0v[reg];   // = -d/2 (<= 0)
                const unsigned pa = (__float_as_uint(da) & 0xFFFFFFE0u) | ord;
                const unsigned ta = max(pa, K1a[T]);
                K1a[T] = min(pa, K1a[T]);
                K2a[T] = min(ta, K2a[T]);
                const float db = a1[T][reg] + e1v[reg];
                const unsigned pb = (__float_as_uint(db) & 0xFFFFFFE0u) | ord;
                const unsigned tb = max(pb, K1b[T]);
                K1b[T] = min(pb, K1b[T]);
                K2b[T] = min(tb, K2b[T]);
            }
        }
        __syncthreads();
    }

    // ---- per tile: unpack (masked score, exact code), merge tracks, then
    // cross-lane top-2 butterfly over QUADS (off 16,32). Float+index compares
    // with explicit lowest-code tie-break -- no further masking. ----
    const int cbase = ncol0 + (quad << 2);
#pragma unroll
    for (int T = 0; T < 2; ++T) {
        const float sa1 = __uint_as_float(K1a[T] & 0xFFFFFFE0u);
        const float sa2 = __uint_as_float(K2a[T] & 0xFFFFFFE0u);
        const float sb1 = __uint_as_float(K1b[T] & 0xFFFFFFE0u);
        const float sb2 = __uint_as_float(K2b[T] & 0xFFFFFFE0u);
        const int ia1 = (int)(((K1a[T] & 31u) >> 2) << 6) + cbase + (int)(K1a[T] & 3u);
        const int ia2 = (int)(((K2a[T] & 31u) >> 2) << 6) + cbase + (int)(K2a[T] & 3u);
        const int ib1 = (int)(((K1b[T] & 31u) >> 2) << 6) + cbase + 16 + (int)(K1b[T] & 3u);
        const int ib2 = (int)(((K2b[T] & 31u) >> 2) << 6) + cbase + 16 + (int)(K2b[T] & 3u);

        // merge tracks (disjoint code sets; bigger score = better)
        float B1, B2; int I1, I2;
        if (sb1 > sa1 || (sb1 == sa1 && ib1 < ia1)) {
            B1 = sb1; I1 = ib1;
            if (sa1 > sb2 || (sa1 == sb2 && ia1 < ib2)) { B2 = sa1; I2 = ia1; }
            else                                        { B2 = sb2; I2 = ib2; }
        } else {
            B1 = sa1; I1 = ia1;
            if (sb1 > sa2 || (sb1 == sa2 && ib1 < ia2)) { B2 = sb1; I2 = ib1; }
            else                                        { B2 = sa2; I2 = ia2; }
        }
#pragma unroll
        for (int off = 16; off <= 32; off <<= 1) {
            const float ob1 = __shfl_xor(B1, off, 64);
            const int   oi1 = __shfl_xor(I1, off, 64);
            const float ob2 = __shfl_xor(B2, off, 64);
            const int   oi2 = __shfl_xor(I2, off, 64);
            if (ob1 > B1 || (ob1 == B1 && oi1 < I1)) {
                float nb2; int ni2;
                if (B1 > ob2 || (B1 == ob2 && I1 < oi2)) { nb2 = B1; ni2 = I1; }
                else                                     { nb2 = ob2; ni2 = oi2; }
                B1 = ob1; I1 = oi1; B2 = nb2; I2 = ni2;
            } else if (ob1 > B2 || (ob1 == B2 && oi1 < I2)) {
                B2 = ob1; I2 = oi1;
            }
        }
        if (lane < 16) {
            const int row = (mset << 5) + (T << 4) + lane;
            b1s[khalf][row] = B1; b2s[khalf][row] = B2;
            i1s[khalf][row] = I1; i2s[khalf][row] = I2;
        }
    }
    __syncthreads();

    // ---- merge halves -> approx top-2 candidates per row (max-flipped) ----
    if (t < 64) {
        const int r0 = t;
        float b1 = b1s[0][r0], b2 = b2s[0][r0];
        int   i1 = i1s[0][r0], i2 = i2s[0][r0];
        const float c1 = b1s[1][r0]; const int j1 = i1s[1][r0];
        const float c2 = b2s[1][r0]; const int j2 = i2s[1][r0];
        if (c1 > b1 || (c1 == b1 && j1 < i1))      { b2 = b1; i2 = i1; b1 = c1; i1 = j1; }
        else if (c1 > b2 || (c1 == b2 && j1 < i2)) { b2 = c1; i2 = j1; }
        if (c2 > b2 || (c2 == b2 && j2 < i2))      { b2 = c2; i2 = j2; }
        c1i[r0] = i1; c2i[r0] = i2;
    }
    __syncthreads();

    // ---- unconditional 4-way-parallel exact fp64 verify of both candidates:
    // thread group k = t>>6 -> candidate (k&1), c-half (k>>1), 32 c each ----
    const int r = t & 63;
    const int k = t >> 6;
    {
        const int ch = k >> 1;
        const int code = (k & 1) ? c2i[r] : c1i[r];
        const float* ep = emb + ((size_t)code << 6) + (ch << 5);
        const float* xq = xb + r;   // lanes r consecutive -> coalesced
        double d0 = 0.0, d1 = 0.0;
#pragma unroll
        for (int cc = 0; cc < 32; cc += 2) {
            const int c = (ch << 5) + cc;
            const double f0 = (double)xq[(size_t)c * HW]       - (double)ep[cc];
            const double f1 = (double)xq[(size_t)(c + 1) * HW] - (double)ep[cc + 1];
            d0 = fma(f0, f0, d0);
            d1 = fma(f1, f1, d1);
        }
        parts[k][r] = d0 + d1;
    }
    __syncthreads();

    // ---- finalize: winner + EXACT fp64 SSE straight from parts[] ----
    int win; double dwin;
    {
        const double d1 = parts[0][r] + parts[2][r];
        const double d2 = parts[1][r] + parts[3][r];
        const int i1 = c1i[r];
        const int i2 = c2i[r];
        win = i1; dwin = d1;
        if (d2 < d1 || (d2 == d1 && i2 < i1)) { win = i2; dwin = d2; } // lowest-index tie-break
    }
    if (t < 64) {
        idx_out[(blk << 6) + r] = (float)win;
        double s = dwin;
#pragma unroll
        for (int off = 32; off > 0; off >>= 1) s += __shfl_down(s, off, 64);
        if (t == 0) ws_sse[blk] = s;    // plain store
    }

    // ---- epilogue: quantized out only (no SSE, no x reads) ----
    {
        const int c0 = k << 4;           // 16 channels per thread-group
        float*       op = out + (size_t)b * CHW + h * 64 + r;
        const float* eq = emb + ((size_t)win << 6) + c0;
#pragma unroll
        for (int cc = 0; cc < 16; ++cc)
            op[(size_t)(c0 + cc) * HW] = eq[cc];
    }
}

// hist2: 16 blocks x 256 threads. LDS histogram of 4096 indices each, pushed
// into a global hist via device atomicAdd (8K adds total), then a done-counter
// last block computes all three scalars. Fence-free R13 pattern (R17-proven).
__global__ void vq_hist2(const float* __restrict__ idx_out,
                         const double* __restrict__ ws_sse,
                         const float* __restrict__ weight,
                         unsigned* __restrict__ hist,
                         unsigned* __restrict__ done,
                         float* __restrict__ scal) {
    __shared__ unsigned hs[512];
    __shared__ double redt[4], reds[4];
    __shared__ int    redi[4], lastf;
    const int t = threadIdx.x;
    const int lane = t & 63, wv = t >> 6;
    hs[t] = 0u; hs[t + 256] = 0u;
    __syncthreads();
    const float4* ip = (const float4*)(idx_out + (blockIdx.x << 12));
#pragma unroll
    for (int i = 0; i < 4; ++i) {
        const float4 v = ip[(i << 8) + t];    // coalesced
        atomicAdd(&hs[(int)v.x], 1u);         // LDS atomics
        atomicAdd(&hs[(int)v.y], 1u);
        atomicAdd(&hs[(int)v.z], 1u);
        atomicAdd(&hs[(int)v.w], 1u);
    }
    __syncthreads();
    if (hs[t])       atomicAdd(&hist[t],       hs[t]);
    if (hs[t + 256]) atomicAdd(&hist[t + 256], hs[t + 256]);
    __syncthreads();   // drains every thread's global atomics (vmcnt 0)

    if (t == 0) {
        lastf = (__hip_atomic_fetch_add(done, 1u, __ATOMIC_RELAXED,
                                        __HIP_MEMORY_SCOPE_AGENT) == 15u) ? 1 : 0;
    }
    __syncthreads();
    if (lastf) {
        double term = 0.0, ssep = 0.0; int act = 0;
#pragma unroll
        for (int j = 0; j < 2; ++j) {
            const int kk = t + (j << 8);
            const unsigned cnt =
                __hip_atomic_load(&hist[kk], __ATOMIC_RELAXED, __HIP_MEMORY_SCOPE_AGENT);
            const double pr = (double)cnt * (1.0 / 65536.0);
            term += pr * log(pr + 1e-10);
            act  += (weight[kk] >= 0.01f) ? 1 : 0;
        }
#pragma unroll
        for (int j = 0; j < 4; ++j) ssep += ws_sse[t + (j << 8)];   // coalesced
#pragma unroll
        for (int off = 32; off > 0; off >>= 1) {
            term += __shfl_down(term, off, 64);
            ssep += __shfl_down(ssep, off, 64);
            act  += __shfl_down(act,  off, 64);
        }
        if (lane == 0) { redt[wv] = term; reds[wv] = ssep; redi[wv] = act; }
        __syncthreads();
        if (t == 0) {
            const double s  = (redt[0] + redt[1]) + (redt[2] + redt[3]);
            const double ss = (reds[0] + reds[1]) + (reds[2] + reds[3]);
            const int    a  = redi[0] + redi[1] + redi[2] + redi[3];
            scal[0] = (float)(ss * (1.0 / 4194304.0));  // commitment_loss
            scal[1] = (float)exp(-s);                   // perplexity
            scal[2] = (float)a;                         // active_codes
        }
    }
}

extern "C" void kernel_launch(void* const* d_in, const int* in_sizes, int n_in,
                              void* d_out, int out_size, void* d_ws, size_t ws_size,
                              hipStream_t stream) {
    const float* x      = (const float*)d_in[0];  // [16,64,64,64] fp32
    const float* emb    = (const float*)d_in[1];  // [512,64] fp32
    const float* weight = (const float*)d_in[2];  // [512] fp32

    float* out = (float*)d_out;
    float*          enorm  = (float*)d_ws;
    unsigned short* pfrag  = (unsigned short*)((char*)d_ws + 4096);
    double*         ws_sse = (double*)((char*)d_ws + 135168);
    unsigned*       hist   = (unsigned*)((char*)d_ws + 143360);
    unsigned*       done   = (unsigned*)((char*)d_ws + 145408);

    float* scal    = out + OUT_ELEMS;      // commitment, perplexity, active
    float* idx_out = out + OUT_ELEMS + 3;  // indices as float [65536]

    vq_prep<<<128, 256, 0, stream>>>(emb, pfrag, enorm, hist, done);
    vq_main<<<1024, 256, 0, stream>>>(x, emb, pfrag, enorm, out, idx_out, ws_sse);
    vq_hist2<<<16, 256, 0, stream>>>(idx_out, ws_sse, weight, hist, done, scal);
}